// Round 12
// baseline (108.806 us; speedup 1.0000x reference)
//
#include <hip/hip_runtime.h>
#include <hip/hip_bf16.h>
#include <cstdint>
#include <cstddef>

typedef __bf16 bf16_t;
typedef bf16_t bf16x8 __attribute__((ext_vector_type(8)));
typedef bf16_t bf16x4 __attribute__((ext_vector_type(4)));
typedef float  f32x4  __attribute__((ext_vector_type(4)));
typedef unsigned int u32;

#define BROWS 4096
#define NV    8192
#define KD    1024
#define NT    32    // GEMM K-tiles (1024 / 32)
#define ST    48    // marginal buckets (6 concepts x 8)
#define NST   64    // state tiles (8192 / 128)
#define LOG2E 1.44269504088896340736f

// async global->LDS, 16B per lane; LDS dst is wave-uniform base + lane*16
#define GLL(gsrc, ldst) \
  __builtin_amdgcn_global_load_lds((const __attribute__((address_space(1))) u32*)(gsrc), \
                                   (__attribute__((address_space(3))) u32*)(ldst), 16, 0, 0)
#define FENCE asm volatile("" ::: "memory")

// ---------------- prep: E/W f32->bf16 + plain S^T indicator, one launch ----
__global__ void prep_kernel(const float* __restrict__ E, const float* __restrict__ W,
                            const int* __restrict__ vs,
                            bf16_t* __restrict__ Eb, bf16_t* __restrict__ Wb,
                            bf16_t* __restrict__ s2t) {
  const int nE = BROWS * KD / 4;       // float4 units
  const int nW = NV * KD / 4;
  const int nS = ST * NV / 8;          // bf16x8 units
  const int nT = nE + nW + nS;
  int idx = blockIdx.x * blockDim.x + threadIdx.x;
  int stride = gridDim.x * blockDim.x;
  for (int i = idx; i < nT; i += stride) {
    if (i < nE + nW) {
      const float4* s; bf16x4* d; int j;
      if (i < nE) { s = (const float4*)E; d = (bf16x4*)Eb; j = i; }
      else        { s = (const float4*)W; d = (bf16x4*)Wb; j = i - nE; }
      float4 v = s[j];
      bf16x4 o;
      o[0] = (bf16_t)v.x; o[1] = (bf16_t)v.y; o[2] = (bf16_t)v.z; o[3] = (bf16_t)v.w;
      d[j] = o;
    } else {
      int u  = i - nE - nW;            // bf16x8 unit of s2t
      int b  = u >> 10;                // bucket row (NV/8 = 1024 units/row)
      int i0 = (u & 1023) * 8;
      int c = b >> 3, d = b & 7, sh = 15 - 3 * c;
      bf16x8 o;
#pragma unroll
      for (int e = 0; e < 8; ++e)
        o[e] = (bf16_t)((((vs[i0 + e] >> sh) & 7) == d) ? 1.0f : 0.0f);
      *(bf16x8*)(s2t + (size_t)b * NV + i0) = o;
    }
  }
}

// ---------------- fused GEMM + exp + marginal (m97 geometry, R6 loop) ----------
// D[i=state][j=batch] = sum_k W[i][k]*E[j][k]; 128x128 tile, BK=32, 4 waves
// (wm x wn = 2x2, wave tile 64 states x 64 batch), 32 KB dbuf LDS + 12 KB s2t.
// 3 blocks/CU (44 KB LDS, ~144 unified regs) -> cross-block TLP hides the
// per-iter barrier/stage stalls (m103: 128^2 = 912 TF vs 256^2 = 792 at this
// exact structure). Per K-tile: {8 frag ds_reads, 4 GLL next tile, 16 MFMA,
// vmcnt(0)+sched_barrier+s_barrier}. Swizzle (T2, 64B rows): phys = logical ^
// ((row&6)<<3); staging source pre-permuted kslot=(l&3)^((l>>3)&3) (rule #21).
// Epilogue: single pass; exp-tile [128 batch][256B] with phys = logical ^
// ((row&7)<<4); s2t tile [48][256B] same swizzle, baked via per-lane source XOR.
__global__ __launch_bounds__(256, 3)
void gemm_fused_kernel(const bf16_t* __restrict__ W, const bf16_t* __restrict__ E,
                       const float* __restrict__ bias, const bf16_t* __restrict__ s2t,
                       float* __restrict__ part) {
  __shared__ __align__(16) char lds[45056];   // [0,32K): dbuf 2x16K; [32K,44K): s2t

  const int t    = threadIdx.x;
  const int lane = t & 63;
  const int wv   = t >> 6;      // 0..3
  const int wm   = wv >> 1;     // 0..1  (state half)
  const int wn   = wv & 1;      // 0..1  (batch half)
  const int fr   = lane & 15;
  const int fq   = lane >> 4;

  // XCD swizzle: 2048 blocks % 8 == 0 -> simple form bijective
  int bid = blockIdx.x;
  int wg  = (bid & 7) * 256 + (bid >> 3);
  const int stile = wg >> 5;    // 0..63 (state tile)
  const int btile = wg & 31;    // 0..31 (batch tile)
  const int st0 = stile * 128;
  const int bt0 = btile * 128;

  // ---- staging geometry: half-tile = 128 rows x 32 k = 8KB = 8 chunks ----
  const int srow = lane >> 2;
  const int skel = ((lane & 3) ^ ((lane >> 3) & 3)) * 8;
  const bf16_t* aptr = W + (size_t)(st0 + wv * 32 + srow) * KD + skel;
  const bf16_t* bptr = E + (size_t)(bt0 + wv * 32 + srow) * KD + skel;
  const int dchunk = wv * 2048;           // wave's chunk-pair base per region

  // ---- ds_read geometry: row stride 64B; phys = logical ^ ((row&6)<<3) ----
  const int xsw    = (fr & 6) << 3;
  const int a_base = wm * 4096 + ((fr * 64 + fq * 16) ^ xsw);
  const int b_base = 8192 + wn * 4096 + ((fr * 64 + fq * 16) ^ xsw);

  f32x4 acc[4][4] = {};

  // ---- prologue: stage kt0 (A then B) + s2t slice (disjoint region) ----
  GLL(aptr,           &lds[0 + dchunk]);
  GLL(aptr + 16 * KD, &lds[0 + dchunk + 1024]);
  GLL(bptr,           &lds[8192 + dchunk]);
  GLL(bptr + 16 * KD, &lds[8192 + dchunk + 1024]);
  {
    // s2t [48 rows][256B] at 32768, 12 chunks of 1KB (4 rows each); wave wv
    // stages chunks 3wv..3wv+2. Lane l: row r = c*4 + (l>>4); source elem
    // pre-swizzled: ((l&15)*8) ^ ((r&7)<<3)  (bakes phys = logical ^ ((r&7)<<4)).
#pragma unroll
    for (int q = 0; q < 3; ++q) {
      const int c = wv * 3 + q;
      const int r = c * 4 + (lane >> 4);
      const bf16_t* src = s2t + (size_t)r * NV + st0 + (((lane & 15) * 8) ^ ((r & 7) << 3));
      GLL(src, &lds[32768 + c * 1024]);
    }
  }
  asm volatile("s_waitcnt vmcnt(0)" ::: "memory");
  __builtin_amdgcn_s_barrier();
  FENCE;

  int cur = 0;
  for (int kt = 0; kt < NT; ++kt) {
    const char* bufp = &lds[cur * 16384];
    char* nbuf = &lds[(cur ^ 1) * 16384];
    const bool pf = (kt + 1 < NT);

    bf16x8 a[4], b[4];
#pragma unroll
    for (int n = 0; n < 4; ++n)
      b[n] = *(const bf16x8*)(bufp + b_base + n * 1024);
#pragma unroll
    for (int m = 0; m < 4; ++m)
      a[m] = *(const bf16x8*)(bufp + a_base + m * 1024);

    if (pf) {
      const bf16_t* an = aptr + (kt + 1) * 32;
      const bf16_t* bn = bptr + (kt + 1) * 32;
      GLL(an,           nbuf + 0 + dchunk);
      GLL(an + 16 * KD, nbuf + 0 + dchunk + 1024);
      GLL(bn,           nbuf + 8192 + dchunk);
      GLL(bn + 16 * KD, nbuf + 8192 + dchunk + 1024);
    }

    __builtin_amdgcn_s_setprio(1);
#pragma unroll
    for (int m = 0; m < 4; ++m)
#pragma unroll
      for (int n = 0; n < 4; ++n)
        acc[m][n] = __builtin_amdgcn_mfma_f32_16x16x32_bf16(a[m], b[n], acc[m][n], 0, 0, 0);
    __builtin_amdgcn_s_setprio(0);

    asm volatile("s_waitcnt vmcnt(0)" ::: "memory");
    __builtin_amdgcn_sched_barrier(0);
    __builtin_amdgcn_s_barrier();
    FENCE;
    cur ^= 1;
  }

  // ================= fused epilogue (single pass) =================
  // exp-tile [128 batch rows][256B] at 0: phys = logical ^ ((row&7)<<4).
#pragma unroll
  for (int m = 0; m < 4; ++m) {
    const float4 bb = *(const float4*)&bias[st0 + wm * 64 + m * 16 + fq * 4];
#pragma unroll
    for (int n = 0; n < 4; ++n) {
      bf16x4 ev;
      ev[0] = (bf16_t)exp2f((acc[m][n][0] + bb.x) * LOG2E);
      ev[1] = (bf16_t)exp2f((acc[m][n][1] + bb.y) * LOG2E);
      ev[2] = (bf16_t)exp2f((acc[m][n][2] + bb.z) * LOG2E);
      ev[3] = (bf16_t)exp2f((acc[m][n][3] + bb.w) * LOG2E);
      const int jh = wn * 64 + n * 16 + fr;             // batch row in tile
      const int ib = wm * 128 + m * 32 + fq * 8;        // state byte in row
      *(bf16x4*)(&lds[jh * 256 + (ib ^ ((fr & 7) << 4))]) = ev;
    }
  }
  __syncthreads();

  // marginal MFMA (16x16x32): wave wv -> batch rows wv*32..+31 (2 groups)
  float* const ppart = part + (size_t)bt0 * (NST * ST) + (size_t)stile * ST;
  f32x4 acc2[2][3] = {};
#pragma unroll
  for (int g = 0; g < 2; ++g)
#pragma unroll
    for (int k2 = 0; k2 < 4; ++k2) {
      const int ko2 = (k2 * 64 + fq * 16) ^ ((fr & 7) << 4);
      const bf16x8 ea = *(const bf16x8*)(&lds[(wv * 32 + g * 16 + fr) * 256 + ko2]);
#pragma unroll
      for (int n2 = 0; n2 < 3; ++n2) {
        const bf16x8 sb = *(const bf16x8*)(&lds[32768 + (n2 * 16 + fr) * 256 + ko2]);
        acc2[g][n2] = __builtin_amdgcn_mfma_f32_16x16x32_bf16(ea, sb, acc2[g][n2], 0, 0, 0);
      }
    }
#pragma unroll
  for (int g = 0; g < 2; ++g) {
    const int jg = wv * 32 + g * 16 + fq * 4;
#pragma unroll
    for (int n2 = 0; n2 < 3; ++n2)
#pragma unroll
      for (int r = 0; r < 4; ++r)
        ppart[(size_t)(jg + r) * (NST * ST) + n2 * 16 + fr] = acc2[g][n2][r];
  }
}

// ---------------- reduce partials over 64 state-tiles + normalize ----------------
// part[batch][stile=64][ST]: each block reads a contiguous 12 KB row.
__global__ __launch_bounds__(64)
void reduce_kernel(const float* __restrict__ part, float* __restrict__ out) {
  const int b = blockIdx.x;
  const int t = threadIdx.x;
  __shared__ float fin[ST];
  if (t < ST) {
    const float* p = part + (size_t)b * (NST * ST) + t;
    float s = 0.f;
#pragma unroll
    for (int mt = 0; mt < NST; ++mt)
      s += p[mt * ST];
    fin[t] = s;
  }
  __syncthreads();
  if (t < ST) {
    float total = fin[0] + fin[1] + fin[2] + fin[3] + fin[4] + fin[5] + fin[6] + fin[7];
    out[(size_t)(t >> 3) * BROWS * 8 + (size_t)b * 8 + (t & 7)] = fin[t] / total;
  }
}

// ---------------- launch ----------------
extern "C" void kernel_launch(void* const* d_in, const int* in_sizes, int n_in,
                              void* d_out, int out_size, void* d_ws, size_t ws_size,
                              hipStream_t stream) {
  const float* E    = (const float*)d_in[0];
  const float* W    = (const float*)d_in[1];
  const float* bias = (const float*)d_in[2];
  const int*   vs   = (const int*)d_in[3];
  float* out = (float*)d_out;

  char* ws = (char*)d_ws;
  size_t off = 0;
  bf16_t* Eb   = (bf16_t*)(ws + off); off += (size_t)BROWS * KD * 2;           // 8 MB
  bf16_t* Wb   = (bf16_t*)(ws + off); off += (size_t)NV * KD * 2;              // 16 MB
  bf16_t* s2t  = (bf16_t*)(ws + off); off += (size_t)ST * NV * 2;              // 786 KB
  float*  part = (float*)(ws + off);  off += (size_t)BROWS * NST * ST * 4;     // 50 MB

  prep_kernel<<<3072, 256, 0, stream>>>(E, W, vs, Eb, Wb, s2t);
  gemm_fused_kernel<<<2048, 256, 0, stream>>>(Wb, Eb, bias, s2t, part);
  reduce_kernel<<<BROWS, 64, 0, stream>>>(part, out);
}